// Round 8
// baseline (140.912 us; speedup 1.0000x reference)
//
#include <hip/hip_runtime.h>

typedef __bf16 bf16x8 __attribute__((ext_vector_type(8)));
typedef float  f32x4  __attribute__((ext_vector_type(4)));

#define CC 64
#define HWSZ 4096
#define CHWSZ 262144
#define NE 512
#define NPIX 131072
#define PIXB 128
#define EPS_MARGIN 0.01f
#define NSTRIPE 32

#define ET_OFF 0              // 512 codes * 256 B (hi64|lo64 bf16), LINEAR rows
#define E2_OFF 131072         // 512 * 4
#define HIST_OFF 133120       // 32 stripes * 512 * 4 = 65536
#define BATCH_OFF 198656      // 32 * 4
#define IDX_OFF 198784        // 131072 * 2 (u16)

__device__ __forceinline__ float bf2f(unsigned short u) {
    unsigned int x = ((unsigned int)u) << 16;
    return __builtin_bit_cast(float, x);
}
__device__ __forceinline__ unsigned short f2bf(float f) {
    unsigned int x = __builtin_bit_cast(unsigned int, f);
    unsigned int r = x + 0x7fffu + ((x >> 16) & 1u);
    return (unsigned short)(r >> 16);
}

// ---- init (8 blocks): exact e2[512]; embed^T hi/lo [code][hi64|lo64] bf16 linear; zero hist/batch ----
__global__ __launch_bounds__(512) void vq_init(const float* __restrict__ eg, char* __restrict__ ws) {
    const int tid = threadIdx.x, blk = blockIdx.x;
    // e2 for this block's 64 codes (coalesced column reads; exact sequential reduce)
    if (tid < 64) {
        int n = blk * 64 + tid;
        float s = 0.f;
        #pragma unroll 8
        for (int k = 0; k < CC; ++k) { float v = eg[k * NE + n]; s = __fadd_rn(s, __fmul_rn(v, v)); }
        ((float*)(ws + E2_OFF))[n] = s;
    }
    // et rows (word-linear, coalesced writes)
    unsigned int* et32 = (unsigned int*)(ws + ET_OFF);
    #pragma unroll
    for (int it = 0; it < 8; ++it) {
        int idx = blk * 4096 + it * 512 + tid;   // global word index
        int n = idx >> 6, w = idx & 63;
        int k = (w & 31) << 1;
        float v0 = eg[k * NE + n], v1 = eg[(k + 1) * NE + n];
        unsigned short c0, c1;
        if (w < 32) { c0 = f2bf(v0); c1 = f2bf(v1); }
        else {
            unsigned short h0 = f2bf(v0), h1 = f2bf(v1);
            c0 = f2bf(__fsub_rn(v0, bf2f(h0)));
            c1 = f2bf(__fsub_rn(v1, bf2f(h1)));
        }
        et32[idx] = (unsigned int)c0 | ((unsigned int)c1 << 16);
    }
    unsigned int* h32 = (unsigned int*)(ws + HIST_OFF);
    for (int i = blk * 2048 + tid; i < (blk + 1) * 2048; i += 512) h32[i] = 0u;
    if (blk == 0 && tid < 32) ((float*)(ws + BATCH_OFF))[tid] = 0.f;
}

// ---- K1: barrier-free split-bf16 MFMA argmin -> idx[] + striped hist ----
// ONE __syncthreads total; B-fragments stream from the L2-hot linear et table.
__global__ __launch_bounds__(256) void vq_argmin(const float* __restrict__ xg,
                                                 const float* __restrict__ eg,
                                                 char* __restrict__ ws) {
    __shared__ __align__(16) char xtb[PIXB * 256];   // [pixel][hi64|lo64] bf16, XOR-swizzled
    __shared__ float e2s[NE];
    __shared__ float xp[4][CC];

    const int tid  = threadIdx.x;
    const int lane = tid & 63;
    const int wv   = tid >> 6;
    const int l15  = lane & 15;
    const int l4   = lane >> 4;
    const int pix0 = blockIdx.x * PIXB;
    const int bb   = pix0 >> 12;
    const size_t xbase = (size_t)bb * CHWSZ + (pix0 & 4095);
    const char* etw = ws + ET_OFF;

    // stage x tile as bf16 hi/lo, swizzled; stage e2s
    {
        const int p = tid & 127, h = tid >> 7;
        const int sw = (p & 15) << 4;
        #pragma unroll
        for (int q = 0; q < 4; ++q) {
            int k0 = h * 32 + q * 8;
            float v[8];
            #pragma unroll
            for (int j = 0; j < 8; ++j) v[j] = xg[xbase + (size_t)(k0 + j) * HWSZ + p];
            unsigned int hw_[4], lw_[4];
            #pragma unroll
            for (int j = 0; j < 4; ++j) {
                unsigned short h0 = f2bf(v[2 * j]), h1 = f2bf(v[2 * j + 1]);
                unsigned short o0 = f2bf(__fsub_rn(v[2 * j], bf2f(h0)));
                unsigned short o1 = f2bf(__fsub_rn(v[2 * j + 1], bf2f(h1)));
                hw_[j] = (unsigned int)h0 | ((unsigned int)h1 << 16);
                lw_[j] = (unsigned int)o0 | ((unsigned int)o1 << 16);
            }
            *(uint4*)(xtb + ((p * 256 + 2 * k0) ^ sw)) = (uint4){hw_[0], hw_[1], hw_[2], hw_[3]};
            *(uint4*)(xtb + ((p * 256 + 128 + 2 * k0) ^ sw)) = (uint4){lw_[0], lw_[1], lw_[2], lw_[3]};
        }
        const float* e2g = (const float*)(ws + E2_OFF);
        for (int t = tid; t < NE; t += 256) e2s[t] = e2g[t];
    }
    __syncthreads();   // the only block-wide barrier

    // A fragments (hi, lo): wave's 32 pixels = 2 m-tiles
    bf16x8 ah[2][2], al[2][2];
    #pragma unroll
    for (int mt = 0; mt < 2; ++mt) {
        int prow = (2 * wv + mt) * 16 + l15;
        int sw = (prow & 15) << 4;
        #pragma unroll
        for (int kh = 0; kh < 2; ++kh) {
            ah[mt][kh] = *(const bf16x8*)(xtb + ((prow * 256 + kh * 64 + l4 * 16) ^ sw));
            al[mt][kh] = *(const bf16x8*)(xtb + ((prow * 256 + 128 + kh * 64 + l4 * 16) ^ sw));
        }
    }

    float minv[2][4], min2v[2][4];
    int   mini[2][4];
    #pragma unroll
    for (int mt = 0; mt < 2; ++mt)
        #pragma unroll
        for (int r = 0; r < 4; ++r) { minv[mt][r] = 3.4e38f; min2v[mt][r] = 3.4e38f; mini[mt][r] = 0; }

    // screen: 32 groups of 16 codes; B direct from global (L1/L2-hot, coalesced 4KB/group)
    #pragma unroll 2
    for (int nt = 0; nt < 32; ++nt) {
        const int code = nt * 16 + l15;
        const char* bp = etw + ((size_t)code << 8) + l4 * 16;
        bf16x8 bh0 = *(const bf16x8*)(bp);
        bf16x8 bh1 = *(const bf16x8*)(bp + 64);
        bf16x8 bl0 = *(const bf16x8*)(bp + 128);
        bf16x8 bl1 = *(const bf16x8*)(bp + 192);
        float e2v = e2s[code];
        #pragma unroll
        for (int mt = 0; mt < 2; ++mt) {
            f32x4 acc = (f32x4){0.f, 0.f, 0.f, 0.f};
            acc = __builtin_amdgcn_mfma_f32_16x16x32_bf16(ah[mt][0], bh0, acc, 0, 0, 0);
            acc = __builtin_amdgcn_mfma_f32_16x16x32_bf16(ah[mt][1], bh1, acc, 0, 0, 0);
            acc = __builtin_amdgcn_mfma_f32_16x16x32_bf16(ah[mt][0], bl0, acc, 0, 0, 0);
            acc = __builtin_amdgcn_mfma_f32_16x16x32_bf16(ah[mt][1], bl1, acc, 0, 0, 0);
            acc = __builtin_amdgcn_mfma_f32_16x16x32_bf16(al[mt][0], bh0, acc, 0, 0, 0);
            acc = __builtin_amdgcn_mfma_f32_16x16x32_bf16(al[mt][1], bh1, acc, 0, 0, 0);
            #pragma unroll
            for (int r2 = 0; r2 < 4; ++r2) {
                float d = __fmaf_rn(-2.f, acc[r2], e2v);
                bool lt = d < minv[mt][r2];
                min2v[mt][r2] = fminf(min2v[mt][r2], fmaxf(d, minv[mt][r2]));
                minv[mt][r2] = lt ? d : minv[mt][r2];
                mini[mt][r2] = lt ? code : mini[mt][r2];
            }
        }
    }

    // 16-lane argmin reduce with second-min tracking and first-index tie-break
    #pragma unroll
    for (int m = 1; m < 16; m <<= 1) {
        #pragma unroll
        for (int mt = 0; mt < 2; ++mt)
            #pragma unroll
            for (int r = 0; r < 4; ++r) {
                float ov  = __shfl_xor(minv[mt][r], m, 64);
                int   oi  = __shfl_xor(mini[mt][r], m, 64);
                float ov2 = __shfl_xor(min2v[mt][r], m, 64);
                bool sel = (ov < minv[mt][r]) || (ov == minv[mt][r] && oi < mini[mt][r]);
                float big = sel ? minv[mt][r] : ov;
                min2v[mt][r] = fminf(fminf(min2v[mt][r], ov2), big);
                minv[mt][r] = sel ? ov : minv[mt][r];
                mini[mt][r] = sel ? oi : mini[mt][r];
            }
    }

    // per-wave exact recheck of near-tie pixels (rare, ~1%) — bit-identical fp32 arithmetic
    #pragma unroll
    for (int mt = 0; mt < 2; ++mt) {
        #pragma unroll
        for (int r = 0; r < 4; ++r) {
            bool fl = (l15 == 0) && (min2v[mt][r] - minv[mt][r] < EPS_MARGIN);
            unsigned long long mask = __ballot(fl);
            while (mask) {
                int l0 = __ffsll((long long)mask) - 1;
                mask &= mask - 1;
                int p = wv * 32 + mt * 16 + ((l0 >> 4) << 2) + r;   // block-local pixel
                xp[wv][lane] = xg[xbase + (size_t)lane * HWSZ + p]; // k = lane (64 lanes)
                float rr[8];
                #pragma unroll
                for (int u = 0; u < 8; ++u) { float v = xp[wv][u]; rr[u] = __fmul_rn(v, v); }
                #pragma unroll
                for (int t2 = 1; t2 < 8; ++t2)
                    #pragma unroll
                    for (int u = 0; u < 8; ++u) { float v = xp[wv][t2 * 8 + u]; rr[u] = __fadd_rn(rr[u], __fmul_rn(v, v)); }
                float f2 = __fadd_rn(__fadd_rn(__fadd_rn(rr[0], rr[1]), __fadd_rn(rr[2], rr[3])),
                                     __fadd_rn(__fadd_rn(rr[4], rr[5]), __fadd_rn(rr[6], rr[7])));
                const int c0 = lane * 8;
                float dot[8];
                #pragma unroll
                for (int j = 0; j < 8; ++j) dot[j] = 0.f;
                #pragma unroll 4
                for (int k = 0; k < CC; ++k) {
                    float xv = xp[wv][k];
                    float4 a = *(const float4*)(eg + k * NE + c0);
                    float4 b = *(const float4*)(eg + k * NE + c0 + 4);
                    dot[0] = __fmaf_rn(xv, a.x, dot[0]); dot[1] = __fmaf_rn(xv, a.y, dot[1]);
                    dot[2] = __fmaf_rn(xv, a.z, dot[2]); dot[3] = __fmaf_rn(xv, a.w, dot[3]);
                    dot[4] = __fmaf_rn(xv, b.x, dot[4]); dot[5] = __fmaf_rn(xv, b.y, dot[5]);
                    dot[6] = __fmaf_rn(xv, b.z, dot[6]); dot[7] = __fmaf_rn(xv, b.w, dot[7]);
                }
                float best = 3.4e38f; int bidx = 0;
                #pragma unroll
                for (int j = 0; j < 8; ++j) {
                    float d = __fadd_rn(__fmaf_rn(-2.f, dot[j], f2), e2s[c0 + j]);
                    if (d < best) { best = d; bidx = c0 + j; }
                }
                #pragma unroll
                for (int m = 1; m < 64; m <<= 1) {
                    float ov = __shfl_xor(best, m, 64);
                    int   oi = __shfl_xor(bidx, m, 64);
                    if (ov < best || (ov == best && oi < bidx)) { best = ov; bidx = oi; }
                }
                int nb = __shfl(bidx, 0, 64);
                if (lane == l0) mini[mt][r] = nb;
            }
        }
    }

    // outputs: idx u16 + striped hist atomics
    if (l15 == 0) {
        unsigned short* idxg = (unsigned short*)(ws + IDX_OFF);
        unsigned int* hist = (unsigned int*)(ws + HIST_OFF) + (blockIdx.x & (NSTRIPE - 1)) * NE;
        #pragma unroll
        for (int mt = 0; mt < 2; ++mt)
            #pragma unroll
            for (int r = 0; r < 4; ++r) {
                int p = wv * 32 + mt * 16 + l4 * 4 + r;
                idxg[pix0 + p] = (unsigned short)mini[mt][r];
                atomicAdd(hist + mini[mt][r], 1u);
            }
    }
}

// ---- K2: streaming apply — block = one (batch, channel) plane of 4096 pixels ----
__global__ __launch_bounds__(256) void vq_apply(const float* __restrict__ xg,
                                                const float* __restrict__ eg,
                                                float* __restrict__ outg,
                                                char* __restrict__ ws) {
    __shared__ float wsum[4];
    const int tid = threadIdx.x, lane = tid & 63, wv = tid >> 6;
    const int bb = blockIdx.x >> 6;          // batch
    const int cc = blockIdx.x & 63;          // channel
    const size_t base = (size_t)bb * CHWSZ + (size_t)cc * HWSZ;
    const unsigned short* idxg = (const unsigned short*)(ws + IDX_OFF) + bb * 4096;
    const float* erow = eg + cc * NE;

    float sq = 0.f;
    #pragma unroll
    for (int it = 0; it < 4; ++it) {
        int p4 = (it * 256 + tid) * 4;
        float4 vr = *(const float4*)(xg + base + p4);
        ushort4 iv = *(const ushort4*)(idxg + p4);
        float q0 = erow[iv.x], q1 = erow[iv.y], q2 = erow[iv.z], q3 = erow[iv.w];
        float vv[4] = {vr.x, vr.y, vr.z, vr.w};
        float qq[4] = {q0, q1, q2, q3};
        float4 ov;
        float* ovp = &ov.x;
        #pragma unroll
        for (int j = 0; j < 4; ++j) {
            float d = __fsub_rn(qq[j], vv[j]);          // exact ref arithmetic
            ovp[j] = __fadd_rn(vv[j], d);
            sq = __fmaf_rn(d, d, sq);
        }
        *(float4*)(outg + base + p4) = ov;
    }
    #pragma unroll
    for (int m = 32; m >= 1; m >>= 1) sq += __shfl_down(sq, m, 64);
    if (lane == 0) wsum[wv] = sq;
    __syncthreads();
    if (tid == 0) atomicAdd((float*)(ws + BATCH_OFF) + bb, wsum[0] + wsum[1] + wsum[2] + wsum[3]);
}

// ---- finalize: sum hist stripes, diff[32], perplexity ----
__global__ __launch_bounds__(512) void vq_fin(const char* __restrict__ ws, float* __restrict__ outg) {
    __shared__ float acc8[8];
    const int tid = threadIdx.x, lane = tid & 63, wv = tid >> 6;
    const unsigned int* h32 = (const unsigned int*)(ws + HIST_OFF);
    unsigned int h = 0;
    #pragma unroll
    for (int s = 0; s < NSTRIPE; ++s) h += h32[s * NE + tid];
    float p = (float)h * (1.f / (float)NPIX);
    float t = p * logf(p + 1e-10f);
    #pragma unroll
    for (int m = 32; m >= 1; m >>= 1) t += __shfl_down(t, m, 64);
    if (lane == 0) acc8[wv] = t;
    __syncthreads();
    if (tid < 32) outg[8388608 + tid] = ((const float*)(ws + BATCH_OFF))[tid] * (1.f / 262144.f);
    if (tid == 0) {
        float s = 0.f;
        #pragma unroll
        for (int u = 0; u < 8; ++u) s += acc8[u];
        outg[8388640] = expf(-s);
    }
}

extern "C" void kernel_launch(void* const* d_in, const int* in_sizes, int n_in,
                              void* d_out, int out_size, void* d_ws, size_t ws_size,
                              hipStream_t stream) {
    const float* xg = (const float*)d_in[0];
    const float* eg = (const float*)d_in[1];
    float* outg = (float*)d_out;
    char* ws = (char*)d_ws;
    vq_init<<<8, 512, 0, stream>>>(eg, ws);
    vq_argmin<<<NPIX / PIXB, 256, 0, stream>>>(xg, eg, ws);
    vq_apply<<<32 * 64, 256, 0, stream>>>(xg, eg, outg, ws);
    vq_fin<<<1, 512, 0, stream>>>(ws, outg);
}

// Round 9
// 103.724 us; speedup vs baseline: 1.3585x; 1.3585x over previous
//
#include <hip/hip_runtime.h>

typedef __bf16 bf16x8 __attribute__((ext_vector_type(8)));
typedef float  f32x4  __attribute__((ext_vector_type(4)));

#define CC 64
#define HWSZ 4096
#define CHWSZ 262144
#define NE 512
#define NPIX 131072
#define PIXB 128
#define EPS_MARGIN 0.01f
#define NSTRIPE 32

#define ET_OFF 0              // 512 codes * 256 B (hi64|lo64 bf16), XOR-swizzled rows
#define E2_OFF 131072         // 512 * 4
#define HIST_OFF 133120       // 32 stripes * 512 * 4 = 65536
#define BATCH_OFF 198656      // 32 * 4
#define IDX_OFF 198784        // 131072 * 2 (u16)

__device__ __forceinline__ float bf2f(unsigned short u) {
    unsigned int x = ((unsigned int)u) << 16;
    return __builtin_bit_cast(float, x);
}
__device__ __forceinline__ unsigned short f2bf(float f) {
    unsigned int x = __builtin_bit_cast(unsigned int, f);
    unsigned int r = x + 0x7fffu + ((x >> 16) & 1u);
    return (unsigned short)(r >> 16);
}
__device__ __forceinline__ void gload16(const void* g, void* l) {
    __builtin_amdgcn_global_load_lds(
        (const __attribute__((address_space(1))) unsigned int*)g,
        (__attribute__((address_space(3))) unsigned int*)l, 16, 0, 0);
}

// ---- init (8 blocks): exact e2[512]; embed^T hi/lo [code][hi64|lo64] bf16 PRE-SWIZZLED ----
__global__ __launch_bounds__(512) void vq_init(const float* __restrict__ eg, char* __restrict__ ws) {
    const int tid = threadIdx.x, blk = blockIdx.x;
    if (tid < 64) {
        int n = blk * 64 + tid;
        float s = 0.f;
        #pragma unroll 8
        for (int k = 0; k < CC; ++k) { float v = eg[k * NE + n]; s = __fadd_rn(s, __fmul_rn(v, v)); }
        ((float*)(ws + E2_OFF))[n] = s;
    }
    char* et = ws + ET_OFF;
    #pragma unroll
    for (int it = 0; it < 8; ++it) {
        int idx = blk * 4096 + it * 512 + tid;   // global word index
        int n = idx >> 6, w = idx & 63;
        int k = (w & 31) << 1;
        float v0 = eg[k * NE + n], v1 = eg[(k + 1) * NE + n];
        unsigned short c0, c1;
        if (w < 32) { c0 = f2bf(v0); c1 = f2bf(v1); }
        else {
            unsigned short h0 = f2bf(v0), h1 = f2bf(v1);
            c0 = f2bf(__fsub_rn(v0, bf2f(h0)));
            c1 = f2bf(__fsub_rn(v1, bf2f(h1)));
        }
        int b = (n * 256 + w * 4) ^ ((n & 15) << 4);   // row-local XOR swizzle (matches reader)
        *(unsigned int*)(et + b) = (unsigned int)c0 | ((unsigned int)c1 << 16);
    }
    unsigned int* h32 = (unsigned int*)(ws + HIST_OFF);
    for (int i = blk * 2048 + tid; i < (blk + 1) * 2048; i += 512) h32[i] = 0u;
    if (blk == 0 && tid < 32) ((float*)(ws + BATCH_OFF))[tid] = 0.f;
}

// ---- K1: split-bf16 MFMA argmin; 2-buffer async et pipeline, ONE barrier per chunk ----
__global__ __launch_bounds__(256) void vq_argmin(const float* __restrict__ xg,
                                                 const float* __restrict__ eg,
                                                 char* __restrict__ ws) {
    __shared__ __align__(16) char sbuf[2][16384];  // phase 1: x tile; phase 2: et dbuf
    __shared__ float e2s[NE];
    __shared__ float xp[4][CC];

    const int tid  = threadIdx.x;
    const int lane = tid & 63;
    const int wv   = tid >> 6;
    const int l15  = lane & 15;
    const int l4   = lane >> 4;
    const int pix0 = blockIdx.x * PIXB;
    const int bb   = pix0 >> 12;
    const size_t xbase = (size_t)bb * CHWSZ + (pix0 & 4095);
    char* xtb = &sbuf[0][0];
    const char* etw = ws + ET_OFF;

    // phase 1: stage x tile as bf16 hi/lo (swizzled), stage e2s
    {
        const int p = tid & 127, h = tid >> 7;
        const int sw = (p & 15) << 4;
        #pragma unroll
        for (int q = 0; q < 4; ++q) {
            int k0 = h * 32 + q * 8;
            float v[8];
            #pragma unroll
            for (int j = 0; j < 8; ++j) v[j] = xg[xbase + (size_t)(k0 + j) * HWSZ + p];
            unsigned int hw_[4], lw_[4];
            #pragma unroll
            for (int j = 0; j < 4; ++j) {
                unsigned short h0 = f2bf(v[2 * j]), h1 = f2bf(v[2 * j + 1]);
                unsigned short o0 = f2bf(__fsub_rn(v[2 * j], bf2f(h0)));
                unsigned short o1 = f2bf(__fsub_rn(v[2 * j + 1], bf2f(h1)));
                hw_[j] = (unsigned int)h0 | ((unsigned int)h1 << 16);
                lw_[j] = (unsigned int)o0 | ((unsigned int)o1 << 16);
            }
            *(uint4*)(xtb + ((p * 256 + 2 * k0) ^ sw)) = (uint4){hw_[0], hw_[1], hw_[2], hw_[3]};
            *(uint4*)(xtb + ((p * 256 + 128 + 2 * k0) ^ sw)) = (uint4){lw_[0], lw_[1], lw_[2], lw_[3]};
        }
        const float* e2g = (const float*)(ws + E2_OFF);
        for (int t = tid; t < NE; t += 256) e2s[t] = e2g[t];
    }
    asm volatile("s_waitcnt lgkmcnt(0)" ::: "memory");
    __builtin_amdgcn_sched_barrier(0);
    __builtin_amdgcn_s_barrier();
    __builtin_amdgcn_sched_barrier(0);

    // A fragments (hi, lo): wave's 32 pixels = 2 m-tiles
    bf16x8 ah[2][2], al[2][2];
    #pragma unroll
    for (int mt = 0; mt < 2; ++mt) {
        int prow = (2 * wv + mt) * 16 + l15;
        int sw = (prow & 15) << 4;
        #pragma unroll
        for (int kh = 0; kh < 2; ++kh) {
            ah[mt][kh] = *(const bf16x8*)(xtb + ((prow * 256 + kh * 64 + l4 * 16) ^ sw));
            al[mt][kh] = *(const bf16x8*)(xtb + ((prow * 256 + 128 + kh * 64 + l4 * 16) ^ sw));
        }
    }
    asm volatile("s_waitcnt lgkmcnt(0)" ::: "memory");
    __builtin_amdgcn_sched_barrier(0);
    __builtin_amdgcn_s_barrier();      // all A-frags in regs; sbuf becomes et dbuf
    __builtin_amdgcn_sched_barrier(0);

    // prologue staging: chunks 0,1 (each wave its 4KB quarter)
    #pragma unroll
    for (int i = 0; i < 4; ++i)
        gload16(etw + 0 * 16384 + wv * 4096 + i * 1024 + lane * 16, &sbuf[0][wv * 4096 + i * 1024]);
    #pragma unroll
    for (int i = 0; i < 4; ++i)
        gload16(etw + 1 * 16384 + wv * 4096 + i * 1024 + lane * 16, &sbuf[1][wv * 4096 + i * 1024]);

    float minv[2][4], min2v[2][4];
    int   mini[2][4];
    #pragma unroll
    for (int mt = 0; mt < 2; ++mt)
        #pragma unroll
        for (int r = 0; r < 4; ++r) { minv[mt][r] = 3.4e38f; min2v[mt][r] = 3.4e38f; mini[mt][r] = 0; }

    for (int c = 0; c < 8; ++c) {
        // chunk c resident (its loads were issued >= one full compute phase ago)
        if (c == 0) { asm volatile("s_waitcnt vmcnt(4)" ::: "memory"); }
        else        { asm volatile("s_waitcnt vmcnt(0)" ::: "memory"); }
        __builtin_amdgcn_sched_barrier(0);
        __builtin_amdgcn_s_barrier();      // ALSO: all waves finished reading chunk c-1
        __builtin_amdgcn_sched_barrier(0);

        // issue chunk c+1 into the buffer freed by chunk c-1 (overlaps with compute c)
        if (c >= 1 && c <= 6) {
            const int cn = c + 1;
            #pragma unroll
            for (int i = 0; i < 4; ++i)
                gload16(etw + (size_t)cn * 16384 + wv * 4096 + i * 1024 + lane * 16,
                        &sbuf[cn & 1][wv * 4096 + i * 1024]);
        }

        const char* buf = &sbuf[c & 1][0];
        #pragma unroll
        for (int nt = 0; nt < 4; ++nt) {
            const int r = nt * 16 + l15;
            const int code = c * 64 + r;
            const int ro = r * 256 + l4 * 16;
            const int sw2 = (r & 15) << 4;
            bf16x8 bh0 = *(const bf16x8*)(buf + ((ro +   0) ^ sw2));
            bf16x8 bh1 = *(const bf16x8*)(buf + ((ro +  64) ^ sw2));
            bf16x8 bl0 = *(const bf16x8*)(buf + ((ro + 128) ^ sw2));
            bf16x8 bl1 = *(const bf16x8*)(buf + ((ro + 192) ^ sw2));
            float e2v = e2s[code];
            #pragma unroll
            for (int mt = 0; mt < 2; ++mt) {
                f32x4 acc = (f32x4){0.f, 0.f, 0.f, 0.f};
                acc = __builtin_amdgcn_mfma_f32_16x16x32_bf16(ah[mt][0], bh0, acc, 0, 0, 0);
                acc = __builtin_amdgcn_mfma_f32_16x16x32_bf16(ah[mt][1], bh1, acc, 0, 0, 0);
                acc = __builtin_amdgcn_mfma_f32_16x16x32_bf16(ah[mt][0], bl0, acc, 0, 0, 0);
                acc = __builtin_amdgcn_mfma_f32_16x16x32_bf16(ah[mt][1], bl1, acc, 0, 0, 0);
                acc = __builtin_amdgcn_mfma_f32_16x16x32_bf16(al[mt][0], bh0, acc, 0, 0, 0);
                acc = __builtin_amdgcn_mfma_f32_16x16x32_bf16(al[mt][1], bh1, acc, 0, 0, 0);
                #pragma unroll
                for (int r2 = 0; r2 < 4; ++r2) {
                    float d = __fmaf_rn(-2.f, acc[r2], e2v);
                    bool lt = d < minv[mt][r2];
                    min2v[mt][r2] = fminf(min2v[mt][r2], fmaxf(d, minv[mt][r2]));
                    minv[mt][r2] = lt ? d : minv[mt][r2];
                    mini[mt][r2] = lt ? code : mini[mt][r2];
                }
            }
        }
    }

    // 16-lane argmin reduce with second-min tracking and first-index tie-break
    #pragma unroll
    for (int m = 1; m < 16; m <<= 1) {
        #pragma unroll
        for (int mt = 0; mt < 2; ++mt)
            #pragma unroll
            for (int r = 0; r < 4; ++r) {
                float ov  = __shfl_xor(minv[mt][r], m, 64);
                int   oi  = __shfl_xor(mini[mt][r], m, 64);
                float ov2 = __shfl_xor(min2v[mt][r], m, 64);
                bool sel = (ov < minv[mt][r]) || (ov == minv[mt][r] && oi < mini[mt][r]);
                float big = sel ? minv[mt][r] : ov;
                min2v[mt][r] = fminf(fminf(min2v[mt][r], ov2), big);
                minv[mt][r] = sel ? ov : minv[mt][r];
                mini[mt][r] = sel ? oi : mini[mt][r];
            }
    }

    // per-wave exact recheck of near-tie pixels (rare) — bit-identical fp32 arithmetic
    #pragma unroll
    for (int mt = 0; mt < 2; ++mt) {
        #pragma unroll
        for (int r = 0; r < 4; ++r) {
            bool fl = (l15 == 0) && (min2v[mt][r] - minv[mt][r] < EPS_MARGIN);
            unsigned long long mask = __ballot(fl);
            while (mask) {
                int l0 = __ffsll((long long)mask) - 1;
                mask &= mask - 1;
                int p = wv * 32 + mt * 16 + ((l0 >> 4) << 2) + r;   // block-local pixel
                xp[wv][lane] = xg[xbase + (size_t)lane * HWSZ + p]; // k = lane
                float rr[8];
                #pragma unroll
                for (int u = 0; u < 8; ++u) { float v = xp[wv][u]; rr[u] = __fmul_rn(v, v); }
                #pragma unroll
                for (int t2 = 1; t2 < 8; ++t2)
                    #pragma unroll
                    for (int u = 0; u < 8; ++u) { float v = xp[wv][t2 * 8 + u]; rr[u] = __fadd_rn(rr[u], __fmul_rn(v, v)); }
                float f2 = __fadd_rn(__fadd_rn(__fadd_rn(rr[0], rr[1]), __fadd_rn(rr[2], rr[3])),
                                     __fadd_rn(__fadd_rn(rr[4], rr[5]), __fadd_rn(rr[6], rr[7])));
                const int c0 = lane * 8;
                float dot[8];
                #pragma unroll
                for (int j = 0; j < 8; ++j) dot[j] = 0.f;
                #pragma unroll 4
                for (int k = 0; k < CC; ++k) {
                    float xv = xp[wv][k];
                    float4 a = *(const float4*)(eg + k * NE + c0);
                    float4 b = *(const float4*)(eg + k * NE + c0 + 4);
                    dot[0] = __fmaf_rn(xv, a.x, dot[0]); dot[1] = __fmaf_rn(xv, a.y, dot[1]);
                    dot[2] = __fmaf_rn(xv, a.z, dot[2]); dot[3] = __fmaf_rn(xv, a.w, dot[3]);
                    dot[4] = __fmaf_rn(xv, b.x, dot[4]); dot[5] = __fmaf_rn(xv, b.y, dot[5]);
                    dot[6] = __fmaf_rn(xv, b.z, dot[6]); dot[7] = __fmaf_rn(xv, b.w, dot[7]);
                }
                float best = 3.4e38f; int bidx = 0;
                #pragma unroll
                for (int j = 0; j < 8; ++j) {
                    float d = __fadd_rn(__fmaf_rn(-2.f, dot[j], f2), e2s[c0 + j]);
                    if (d < best) { best = d; bidx = c0 + j; }
                }
                #pragma unroll
                for (int m = 1; m < 64; m <<= 1) {
                    float ov = __shfl_xor(best, m, 64);
                    int   oi = __shfl_xor(bidx, m, 64);
                    if (ov < best || (ov == best && oi < bidx)) { best = ov; bidx = oi; }
                }
                int nb = __shfl(bidx, 0, 64);
                if (lane == l0) mini[mt][r] = nb;
            }
        }
    }

    // outputs: idx u16 + striped hist atomics
    if (l15 == 0) {
        unsigned short* idxg = (unsigned short*)(ws + IDX_OFF);
        unsigned int* hist = (unsigned int*)(ws + HIST_OFF) + (blockIdx.x & (NSTRIPE - 1)) * NE;
        #pragma unroll
        for (int mt = 0; mt < 2; ++mt)
            #pragma unroll
            for (int r = 0; r < 4; ++r) {
                int p = wv * 32 + mt * 16 + l4 * 4 + r;
                idxg[pix0 + p] = (unsigned short)mini[mt][r];
                atomicAdd(hist + mini[mt][r], 1u);
            }
    }
}

// ---- K2: streaming apply — block = one (batch, channel) plane of 4096 pixels ----
__global__ __launch_bounds__(256) void vq_apply(const float* __restrict__ xg,
                                                const float* __restrict__ eg,
                                                float* __restrict__ outg,
                                                char* __restrict__ ws) {
    __shared__ float wsum[4];
    const int tid = threadIdx.x, lane = tid & 63, wv = tid >> 6;
    const int bb = blockIdx.x >> 6;          // batch
    const int cc = blockIdx.x & 63;          // channel
    const size_t base = (size_t)bb * CHWSZ + (size_t)cc * HWSZ;
    const unsigned short* idxg = (const unsigned short*)(ws + IDX_OFF) + bb * 4096;
    const float* erow = eg + cc * NE;

    float sq = 0.f;
    #pragma unroll
    for (int it = 0; it < 4; ++it) {
        int p4 = (it * 256 + tid) * 4;
        float4 vr = *(const float4*)(xg + base + p4);
        ushort4 iv = *(const ushort4*)(idxg + p4);
        float q0 = erow[iv.x], q1 = erow[iv.y], q2 = erow[iv.z], q3 = erow[iv.w];
        float vv[4] = {vr.x, vr.y, vr.z, vr.w};
        float qq[4] = {q0, q1, q2, q3};
        float4 ov;
        float* ovp = &ov.x;
        #pragma unroll
        for (int j = 0; j < 4; ++j) {
            float d = __fsub_rn(qq[j], vv[j]);          // exact ref arithmetic
            ovp[j] = __fadd_rn(vv[j], d);
            sq = __fmaf_rn(d, d, sq);
        }
        *(float4*)(outg + base + p4) = ov;
    }
    #pragma unroll
    for (int m = 32; m >= 1; m >>= 1) sq += __shfl_down(sq, m, 64);
    if (lane == 0) wsum[wv] = sq;
    __syncthreads();
    if (tid == 0) atomicAdd((float*)(ws + BATCH_OFF) + bb, wsum[0] + wsum[1] + wsum[2] + wsum[3]);
}

// ---- finalize: sum hist stripes, diff[32], perplexity ----
__global__ __launch_bounds__(512) void vq_fin(const char* __restrict__ ws, float* __restrict__ outg) {
    __shared__ float acc8[8];
    const int tid = threadIdx.x, lane = tid & 63, wv = tid >> 6;
    const unsigned int* h32 = (const unsigned int*)(ws + HIST_OFF);
    unsigned int h = 0;
    #pragma unroll
    for (int s = 0; s < NSTRIPE; ++s) h += h32[s * NE + tid];
    float p = (float)h * (1.f / (float)NPIX);
    float t = p * logf(p + 1e-10f);
    #pragma unroll
    for (int m = 32; m >= 1; m >>= 1) t += __shfl_down(t, m, 64);
    if (lane == 0) acc8[wv] = t;
    __syncthreads();
    if (tid < 32) outg[8388608 + tid] = ((const float*)(ws + BATCH_OFF))[tid] * (1.f / 262144.f);
    if (tid == 0) {
        float s = 0.f;
        #pragma unroll
        for (int u = 0; u < 8; ++u) s += acc8[u];
        outg[8388640] = expf(-s);
    }
}

extern "C" void kernel_launch(void* const* d_in, const int* in_sizes, int n_in,
                              void* d_out, int out_size, void* d_ws, size_t ws_size,
                              hipStream_t stream) {
    const float* xg = (const float*)d_in[0];
    const float* eg = (const float*)d_in[1];
    float* outg = (float*)d_out;
    char* ws = (char*)d_ws;
    vq_init<<<8, 512, 0, stream>>>(eg, ws);
    vq_argmin<<<NPIX / PIXB, 256, 0, stream>>>(xg, eg, ws);
    vq_apply<<<32 * 64, 256, 0, stream>>>(xg, eg, outg, ws);
    vq_fin<<<1, 512, 0, stream>>>(ws, outg);
}